// Round 10
// baseline (70.078 us; speedup 1.0000x reference)
//
#include <hip/hip_runtime.h>

// Problem: N=65536 rows, H=512, E=8, OUT=2.
//   oh=x[:,0:8], delta=x[:,8], phi=x[:,9]
//   h  = relu(delta*w1 + b1 + phi*(oh@meta_w) + oh@meta_b)   -> one K=32 bf16 MFMA GEMM
//   h2 = relu(h @ w2 + b2)                                   -> main GEMM, 32x32x16 bf16 MFMA
//   out = h2 @ w3 + b3                                       -> fused shuffle-reduce epilogue
//
// R10: layer-2 switched to mfma_f32_32x32x16_bf16. Same 64x64 wave tile
// (acc = 4x f32x16 = 64 AGPR) but per K=16 sub-step only af 8 + bf 8 = 16
// data VGPRs (half of the 16x16 path) -> ~50 VGPR + 64 AGPR = ~114 < 128,
// so __launch_bounds__(512,4) (2 blocks/CU, 4 waves/SIMD) fits with NO spill
// (R5/R9 spilled 22MB at this cap). Fragment pack order ((k>>3)*512+c)*8+(k&7)
// is identical for both MFMA shapes -> prep and layer-1 unchanged.

#define BM 64

typedef float f32x4  __attribute__((ext_vector_type(4)));
typedef float f32x16 __attribute__((ext_vector_type(16)));
typedef short s16x8  __attribute__((ext_vector_type(8)));

__device__ __forceinline__ short f2bf(float f) {
    union { float f; unsigned u; } c; c.f = f;
    unsigned u = c.u;
    return (short)((u + 0x7FFFu + ((u >> 16) & 1u)) >> 16);  // RNE
}

// ---------------- prep: build bf16 weight images in workspace ----------------
// w2s layout: [c8=k>>3][n=512][j=k&7] bf16  (fragment order, valid for both
//   16x16x32 and 32x32x16 paths: k-group = 8 contiguous k per lane-group)
// waugS layout: [col=512][k=32] bf16, rows of W' = [meta_w(8); meta_b(8); w1; b1; 0...]
__global__ void prep_kernel(const float* __restrict__ w1, const float* __restrict__ b1,
                            const float* __restrict__ mw, const float* __restrict__ mb,
                            const float* __restrict__ w2,
                            short* __restrict__ w2s, short* __restrict__ waugS) {
    int id = blockIdx.x * 256 + threadIdx.x;
    if (id < 512 * 512) {
        int k = id / 512, n = id % 512;
        w2s[((k >> 3) * 512 + n) * 8 + (k & 7)] = f2bf(w2[id]);
    }
    if (id < 512 * 32) {
        int col = id >> 5, k = id & 31;
        float v = 0.f;
        if (k < 8)        v = mw[k * 512 + col];
        else if (k < 16)  v = mb[(k - 8) * 512 + col];
        else if (k == 16) v = w1[col];
        else if (k == 17) v = b1[col];
        waugS[col * 32 + k] = f2bf(v);
    }
}

// ---------------- fused MLP ----------------
// grid 1024 blocks x 512 threads (8 waves). Block tile: 64 rows x 512 cols.
// Wave w owns cols [w*64, w*64+64), all 64 rows -> acc 2(mb) x 2(cb) 32x32 frags.
__global__ __launch_bounds__(512, 4) void fused_mlp(
    const float* __restrict__ x, const short* __restrict__ waugS,
    const short* __restrict__ w2s, const float* __restrict__ b2,
    const float* __restrict__ w3, const float* __restrict__ b3,
    float* __restrict__ out) {

    // h in FRAGMENT order: short idx = (c>>3)*512 + row*8 + (c&7)
    __shared__ __align__(16) short haug[64 * 512];          // 64KB
    __shared__ float xls[64 * 10];                          // 2560 B
    __shared__ float oacc[128];                             // 512 B

    const int tid  = threadIdx.x;
    const int wv   = tid >> 6;           // 0..7
    const int lane = tid & 63;
    const int l15  = lane & 15;
    const int g    = lane >> 4;
    const int hi   = lane >> 5;          // 0..1
    const int l31  = lane & 31;
    const long rowbase = (long)blockIdx.x * BM;

    // ---- load x tile (64x10 f32 = 640 floats, strided over 512 thr), zero out-acc ----
    for (int i = tid; i < BM * 10; i += 512) xls[i] = x[rowbase * 10 + i];
    if (tid < 128) oacc[tid] = 0.f;
    __syncthreads();

    // ---- layer 1: one K=32 MFMA pass (16x16x32); h -> LDS in fragment order ----
    {
        s16x8 afr[4];
#pragma unroll
        for (int m = 0; m < 4; ++m) {
            int r = m * 16 + l15;
            float v[8];
            if (g == 0) {                    // k=0..7 : oh * phi
                float phi = xls[r * 10 + 9];
#pragma unroll
                for (int j = 0; j < 8; ++j) v[j] = xls[r * 10 + j] * phi;
            } else if (g == 1) {             // k=8..15 : oh
#pragma unroll
                for (int j = 0; j < 8; ++j) v[j] = xls[r * 10 + j];
            } else if (g == 2) {             // k=16,17 : delta, 1
                v[0] = xls[r * 10 + 8]; v[1] = 1.f;
#pragma unroll
                for (int j = 2; j < 8; ++j) v[j] = 0.f;
            } else {                         // k=24..31 : 0
#pragma unroll
                for (int j = 0; j < 8; ++j) v[j] = 0.f;
            }
            s16x8 a;
#pragma unroll
            for (int j = 0; j < 8; ++j) a[j] = f2bf(v[j]);
            afr[m] = a;
        }
#pragma unroll
        for (int nf = 0; nf < 4; ++nf) {
            int col = wv * 64 + nf * 16 + l15;
            s16x8 bfr = *(const s16x8*)(waugS + col * 32 + g * 8);
            int chi = (col >> 3) * 512 + (col & 7);          // fragment-order column part
#pragma unroll
            for (int m = 0; m < 4; ++m) {
                f32x4 c = {0.f, 0.f, 0.f, 0.f};
                c = __builtin_amdgcn_mfma_f32_16x16x32_bf16(afr[m], bfr, c, 0, 0, 0);
#pragma unroll
                for (int r4 = 0; r4 < 4; ++r4) {
                    int row = m * 16 + g * 4 + r4;
                    float hv = c[r4];
                    hv = hv > 0.f ? hv : 0.f;
                    haug[chi + row * 8] = f2bf(hv);
                }
            }
        }
    }
    __syncthreads();   // h ready; haug read-only from here -> no more barriers

    // ---- layer 2: K=512 in 32 sub-steps of 16 (32x32x16 MFMA), barrier-free ----
    f32x16 acc[2][2];
#pragma unroll
    for (int a = 0; a < 2; ++a)
#pragma unroll
        for (int b = 0; b < 2; ++b)
#pragma unroll
            for (int e = 0; e < 16; ++e) acc[a][b][e] = 0.f;

    // af (A=h): byte = (s*2+hi)*1024 + (mb*32+l31)*16 ; imm = s*2048 + mb*512
    const char* habase = (const char*)haug + hi * 1024 + l31 * 16;
    // bf (B=w2): s16x8 index = (s*2+hi)*512 + wv*64 + cb*32 + l31
    const s16x8* __restrict__ w2base = (const s16x8*)w2s + hi * 512 + wv * 64 + l31;

#pragma unroll 4
    for (int s = 0; s < 32; ++s) {
        s16x8 b0 = w2base[s * 1024];
        s16x8 b1 = w2base[s * 1024 + 32];
        s16x8 a0 = *(const s16x8*)(habase + s * 2048);
        s16x8 a1 = *(const s16x8*)(habase + s * 2048 + 512);
        acc[0][0] = __builtin_amdgcn_mfma_f32_32x32x16_bf16(a0, b0, acc[0][0], 0, 0, 0);
        acc[0][1] = __builtin_amdgcn_mfma_f32_32x32x16_bf16(a0, b1, acc[0][1], 0, 0, 0);
        acc[1][0] = __builtin_amdgcn_mfma_f32_32x32x16_bf16(a1, b0, acc[1][0], 0, 0, 0);
        acc[1][1] = __builtin_amdgcn_mfma_f32_32x32x16_bf16(a1, b1, acc[1][1], 0, 0, 0);
    }

    // ---- layer 3: relu(acc+b2) @ w3, per-(mb,reg) immediate reduce ----
    // C/D 32x32 layout: col = l31, row = (reg&3) + 8*(reg>>2) + 4*hi   [m74/m101]
    float b2c[2], w30c[2], w31c[2];
#pragma unroll
    for (int cb = 0; cb < 2; ++cb) {
        int c = wv * 64 + cb * 32 + l31;
        b2c[cb] = b2[c];
        w30c[cb] = w3[c * 2 + 0];
        w31c[cb] = w3[c * 2 + 1];
    }
#pragma unroll
    for (int mb = 0; mb < 2; ++mb) {
#pragma unroll
        for (int reg = 0; reg < 16; ++reg) {
            float s0 = 0.f, s1 = 0.f;
#pragma unroll
            for (int cb = 0; cb < 2; ++cb) {
                float v = acc[mb][cb][reg] + b2c[cb];
                v = v > 0.f ? v : 0.f;
                s0 += v * w30c[cb];
                s1 += v * w31c[cb];
            }
            s0 += __shfl_xor(s0, 1);  s1 += __shfl_xor(s1, 1);
            s0 += __shfl_xor(s0, 2);  s1 += __shfl_xor(s1, 2);
            s0 += __shfl_xor(s0, 4);  s1 += __shfl_xor(s1, 4);
            s0 += __shfl_xor(s0, 8);  s1 += __shfl_xor(s1, 8);
            s0 += __shfl_xor(s0, 16); s1 += __shfl_xor(s1, 16);
            if (l31 == 0) {
                int row = mb * 32 + (reg & 3) + 8 * (reg >> 2) + 4 * hi;
                atomicAdd(&oacc[row * 2 + 0], s0);
                atomicAdd(&oacc[row * 2 + 1], s1);
            }
        }
    }
    __syncthreads();

    if (tid < 128) {
        int row = tid >> 1, o = tid & 1;
        out[(rowbase + row) * 2 + o] = oacc[tid] + b3[o];
    }
}

extern "C" void kernel_launch(void* const* d_in, const int* in_sizes, int n_in,
                              void* d_out, int out_size, void* d_ws, size_t ws_size,
                              hipStream_t stream) {
    const float* x  = (const float*)d_in[0];
    const float* w1 = (const float*)d_in[1];
    const float* b1 = (const float*)d_in[2];
    const float* mw = (const float*)d_in[3];
    const float* mb = (const float*)d_in[4];
    const float* w2 = (const float*)d_in[5];
    const float* b2 = (const float*)d_in[6];
    const float* w3 = (const float*)d_in[7];
    const float* b3 = (const float*)d_in[8];
    float* out = (float*)d_out;

    short* w2s   = (short*)d_ws;          // 512 KB
    short* waugS = w2s + 512 * 512;       // 32 KB

    prep_kernel<<<1024, 256, 0, stream>>>(w1, b1, mw, mb, w2, w2s, waugS);
    fused_mlp<<<65536 / BM, 512, 0, stream>>>(x, waugS, w2s, b2, w3, b3, out);
}

// Round 11
// 53.942 us; speedup vs baseline: 1.2991x; 1.2991x over previous
//
#include <hip/hip_runtime.h>

// Problem: N=65536 rows, H=512, E=8, OUT=2.
//   oh=x[:,0:8], delta=x[:,8], phi=x[:,9]
//   h  = relu(delta*w1 + b1 + phi*(oh@meta_w) + oh@meta_b)   -> one K=32 bf16 MFMA GEMM
//   h2 = relu(h @ w2 + b2)                                   -> main GEMM, bf16 MFMA, K=512
//   out = h2 @ w3 + b3                                       -> fused shuffle-reduce epilogue
//
// R11: R9 shape (16x16x32, m4c4, 64x64 wave tile, 8 waves, (512,4) cap) with a
// register diet to hit the 64-VGPR VALU budget (acc=64 AGPR is the other half
// of the 128 unified cap):
//   - #pragma unroll 1 on K-loop: stops full-unroll load hoisting (R9's spill)
//   - split-af: bf0..3 (globals, long latency) + af0/af1 up front -> 8 MFMA
//     -> sched_barrier -> af2/af3 reload (LDS, ~120cy, regs reused) -> 8 MFMA
//     peak VALU live ~54 regs; mid-iter LDS stall covered by 4 waves/SIMD
//   - pointer-increment addressing, imm offsets (no per-frag address math)

#define BM 64

typedef float f32x4 __attribute__((ext_vector_type(4)));
typedef short s16x8 __attribute__((ext_vector_type(8)));

__device__ __forceinline__ short f2bf(float f) {
    union { float f; unsigned u; } c; c.f = f;
    unsigned u = c.u;
    return (short)((u + 0x7FFFu + ((u >> 16) & 1u)) >> 16);  // RNE
}

// ---------------- prep: build bf16 weight images in workspace ----------------
// w2s layout: [ks=16][g=4][n=512][j=8] bf16  (B-fragment order)
//   element (ks,g,n,j) = w2[k][n] with k = ks*32 + g*8 + j
// waugS layout: [col=512][k=32] bf16, rows of W' = [meta_w(8); meta_b(8); w1; b1; 0...]
__global__ void prep_kernel(const float* __restrict__ w1, const float* __restrict__ b1,
                            const float* __restrict__ mw, const float* __restrict__ mb,
                            const float* __restrict__ w2,
                            short* __restrict__ w2s, short* __restrict__ waugS) {
    int id = blockIdx.x * 256 + threadIdx.x;
    if (id < 512 * 512) {
        int k = id / 512, n = id % 512;
        int ks = k >> 5, g = (k >> 3) & 3, j = k & 7;
        w2s[(((ks * 4 + g) * 512) + n) * 8 + j] = f2bf(w2[id]);
    }
    if (id < 512 * 32) {
        int col = id >> 5, k = id & 31;
        float v = 0.f;
        if (k < 8)        v = mw[k * 512 + col];
        else if (k < 16)  v = mb[(k - 8) * 512 + col];
        else if (k == 16) v = w1[col];
        else if (k == 17) v = b1[col];
        waugS[col * 32 + k] = f2bf(v);
    }
}

// ---------------- fused MLP ----------------
// grid 1024 blocks x 512 threads (8 waves). Block tile: 64 rows x 512 cols.
// Wave w owns cols [w*64, w*64+64), all 64 rows -> acc 4(m) x 4(n) frags.
__global__ __launch_bounds__(512, 4) void fused_mlp(
    const float* __restrict__ x, const short* __restrict__ waugS,
    const short* __restrict__ w2s, const float* __restrict__ b2,
    const float* __restrict__ w3, const float* __restrict__ b3,
    float* __restrict__ out) {

    // h in FRAGMENT order: short idx = (k>>3)*512 + row*8 + (k&7)
    __shared__ __align__(16) short haug[64 * 512];          // 64KB
    __shared__ float xls[64 * 10];                          // 2560 B
    __shared__ float oacc[128];                             // 512 B

    const int tid  = threadIdx.x;
    const int wv   = tid >> 6;           // 0..7
    const int lane = tid & 63;
    const int l15  = lane & 15;
    const int g    = lane >> 4;
    const long rowbase = (long)blockIdx.x * BM;

    // ---- load x tile (64x10 f32 = 640 floats, strided over 512 thr), zero out-acc ----
    for (int i = tid; i < BM * 10; i += 512) xls[i] = x[rowbase * 10 + i];
    if (tid < 128) oacc[tid] = 0.f;
    __syncthreads();

    // ---- layer 1: one K=32 MFMA pass; h -> LDS in fragment order ----
    {
        s16x8 afr[4];
#pragma unroll
        for (int m = 0; m < 4; ++m) {
            int r = m * 16 + l15;
            float v[8];
            if (g == 0) {                    // k=0..7 : oh * phi
                float phi = xls[r * 10 + 9];
#pragma unroll
                for (int j = 0; j < 8; ++j) v[j] = xls[r * 10 + j] * phi;
            } else if (g == 1) {             // k=8..15 : oh
#pragma unroll
                for (int j = 0; j < 8; ++j) v[j] = xls[r * 10 + j];
            } else if (g == 2) {             // k=16,17 : delta, 1
                v[0] = xls[r * 10 + 8]; v[1] = 1.f;
#pragma unroll
                for (int j = 2; j < 8; ++j) v[j] = 0.f;
            } else {                         // k=24..31 : 0
#pragma unroll
                for (int j = 0; j < 8; ++j) v[j] = 0.f;
            }
            s16x8 a;
#pragma unroll
            for (int j = 0; j < 8; ++j) a[j] = f2bf(v[j]);
            afr[m] = a;
        }
#pragma unroll
        for (int nf = 0; nf < 4; ++nf) {
            int col = wv * 64 + nf * 16 + l15;
            s16x8 bfr = *(const s16x8*)(waugS + col * 32 + g * 8);
            int chi = (col >> 3) * 512 + (col & 7);          // fragment-order column part
#pragma unroll
            for (int m = 0; m < 4; ++m) {
                f32x4 c = {0.f, 0.f, 0.f, 0.f};
                c = __builtin_amdgcn_mfma_f32_16x16x32_bf16(afr[m], bfr, c, 0, 0, 0);
#pragma unroll
                for (int r4 = 0; r4 < 4; ++r4) {
                    int row = m * 16 + g * 4 + r4;
                    float hv = c[r4];
                    hv = hv > 0.f ? hv : 0.f;
                    haug[chi + row * 8] = f2bf(hv);
                }
            }
        }
    }
    __syncthreads();   // h ready; haug read-only from here -> no more barriers

    // ---- layer 2: K=512 in 16 steps of 32; unroll 1, split-af schedule ----
    f32x4 acc[4][4];
#pragma unroll
    for (int m = 0; m < 4; ++m)
#pragma unroll
        for (int n = 0; n < 4; ++n) acc[m][n] = (f32x4){0.f, 0.f, 0.f, 0.f};

    // bf: byte addr = ((t*4+g)*512 + wv*64 + n*16 + l15)*16 ; per-t stride 32768B
    const char* bfp = (const char*)w2s + (g * 512 + wv * 64 + l15) * 16;
    // af: byte addr = t*4096 + g*1024 + m*256 + l15*16 ; per-t stride 4096B
    const char* hbp = (const char*)haug + g * 1024 + l15 * 16;

#pragma unroll 1
    for (int t = 0; t < 16; ++t) {
        s16x8 bf0 = *(const s16x8*)(bfp);
        s16x8 bf1 = *(const s16x8*)(bfp + 256);
        s16x8 bf2 = *(const s16x8*)(bfp + 512);
        s16x8 bf3 = *(const s16x8*)(bfp + 768);
        s16x8 a0  = *(const s16x8*)(hbp);
        s16x8 a1  = *(const s16x8*)(hbp + 256);
        acc[0][0] = __builtin_amdgcn_mfma_f32_16x16x32_bf16(a0, bf0, acc[0][0], 0, 0, 0);
        acc[0][1] = __builtin_amdgcn_mfma_f32_16x16x32_bf16(a0, bf1, acc[0][1], 0, 0, 0);
        acc[0][2] = __builtin_amdgcn_mfma_f32_16x16x32_bf16(a0, bf2, acc[0][2], 0, 0, 0);
        acc[0][3] = __builtin_amdgcn_mfma_f32_16x16x32_bf16(a0, bf3, acc[0][3], 0, 0, 0);
        acc[1][0] = __builtin_amdgcn_mfma_f32_16x16x32_bf16(a1, bf0, acc[1][0], 0, 0, 0);
        acc[1][1] = __builtin_amdgcn_mfma_f32_16x16x32_bf16(a1, bf1, acc[1][1], 0, 0, 0);
        acc[1][2] = __builtin_amdgcn_mfma_f32_16x16x32_bf16(a1, bf2, acc[1][2], 0, 0, 0);
        acc[1][3] = __builtin_amdgcn_mfma_f32_16x16x32_bf16(a1, bf3, acc[1][3], 0, 0, 0);
        __builtin_amdgcn_sched_barrier(0);   // pin af2/af3 loads here (reuse a0/a1 regs)
        s16x8 a2  = *(const s16x8*)(hbp + 512);
        s16x8 a3  = *(const s16x8*)(hbp + 768);
        acc[2][0] = __builtin_amdgcn_mfma_f32_16x16x32_bf16(a2, bf0, acc[2][0], 0, 0, 0);
        acc[2][1] = __builtin_amdgcn_mfma_f32_16x16x32_bf16(a2, bf1, acc[2][1], 0, 0, 0);
        acc[2][2] = __builtin_amdgcn_mfma_f32_16x16x32_bf16(a2, bf2, acc[2][2], 0, 0, 0);
        acc[2][3] = __builtin_amdgcn_mfma_f32_16x16x32_bf16(a2, bf3, acc[2][3], 0, 0, 0);
        acc[3][0] = __builtin_amdgcn_mfma_f32_16x16x32_bf16(a3, bf0, acc[3][0], 0, 0, 0);
        acc[3][1] = __builtin_amdgcn_mfma_f32_16x16x32_bf16(a3, bf1, acc[3][1], 0, 0, 0);
        acc[3][2] = __builtin_amdgcn_mfma_f32_16x16x32_bf16(a3, bf2, acc[3][2], 0, 0, 0);
        acc[3][3] = __builtin_amdgcn_mfma_f32_16x16x32_bf16(a3, bf3, acc[3][3], 0, 0, 0);
        bfp += 32768;
        hbp += 4096;
    }

    // ---- layer 3: relu(acc+b2) @ w3, per-(m,r4) immediate reduce (low reg pressure) ----
    float bb2[4], w30[4], w31[4];
#pragma unroll
    for (int n = 0; n < 4; ++n) {
        int col = wv * 64 + n * 16 + l15;
        bb2[n] = b2[col];
        w30[n] = w3[col * 2 + 0];
        w31[n] = w3[col * 2 + 1];
    }
#pragma unroll
    for (int m = 0; m < 4; ++m) {
#pragma unroll
        for (int r4 = 0; r4 < 4; ++r4) {
            float s0 = 0.f, s1 = 0.f;
#pragma unroll
            for (int n = 0; n < 4; ++n) {
                float v = acc[m][n][r4] + bb2[n];
                v = v > 0.f ? v : 0.f;
                s0 += v * w30[n];
                s1 += v * w31[n];
            }
            s0 += __shfl_xor(s0, 1); s1 += __shfl_xor(s1, 1);
            s0 += __shfl_xor(s0, 2); s1 += __shfl_xor(s1, 2);
            s0 += __shfl_xor(s0, 4); s1 += __shfl_xor(s1, 4);
            s0 += __shfl_xor(s0, 8); s1 += __shfl_xor(s1, 8);
            if (l15 == 0) {
                int row = m * 16 + g * 4 + r4;
                atomicAdd(&oacc[row * 2 + 0], s0);
                atomicAdd(&oacc[row * 2 + 1], s1);
            }
        }
    }
    __syncthreads();

    if (tid < 128) {
        int row = tid >> 1, o = tid & 1;
        out[(rowbase + row) * 2 + o] = oacc[tid] + b3[o];
    }
}

extern "C" void kernel_launch(void* const* d_in, const int* in_sizes, int n_in,
                              void* d_out, int out_size, void* d_ws, size_t ws_size,
                              hipStream_t stream) {
    const float* x  = (const float*)d_in[0];
    const float* w1 = (const float*)d_in[1];
    const float* b1 = (const float*)d_in[2];
    const float* mw = (const float*)d_in[3];
    const float* mb = (const float*)d_in[4];
    const float* w2 = (const float*)d_in[5];
    const float* b2 = (const float*)d_in[6];
    const float* w3 = (const float*)d_in[7];
    const float* b3 = (const float*)d_in[8];
    float* out = (float*)d_out;

    short* w2s   = (short*)d_ws;          // 512 KB
    short* waugS = w2s + 512 * 512;       // 32 KB

    prep_kernel<<<1024, 256, 0, stream>>>(w1, b1, mw, mb, w2, w2s, waugS);
    fused_mlp<<<65536 / BM, 512, 0, stream>>>(x, waugS, w2s, b2, w3, b3, out);
}